// Round 5
// baseline (531.598 us; speedup 1.0000x reference)
//
#include <hip/hip_runtime.h>

// Transposed (channel) attention via Gram decomposition, fp32, MI355X.
// b=4, c=256, n=16384.
//   G = X X^T (per batch), s = X 1
//   scores = Wq G Wk^T + (Wq s) bk^T + bq (Wk s)^T + n bq bk^T
//   P = softmax(scores/16);  M = P Wv;  r = P bv
//   out = M X + r 1^T + x
//
// Memory plan (crash de-risk, R3): big intermediates (Gp 32MB, G 1MB, T 1MB)
// live inside d_out (64 MB), which k_out fully overwrites at the end and
// never reads. Workspace holds only M/s/r (~1.02 MB) — survives even a
// tiny ws_size.
// Pipeline: k_rowsum -> k_gram (split-K) -> k_red -> k_T -> k_soft -> k_out

#define BB 4
#define CC 256
#define NN 16384
#define NCH 32
#define CHK (NN / NCH) // 512

// ---------------------------------------------------------------------------
// s[b][c] = sum_n X[b][c][n].  Grid: BB*CC blocks x 256 threads.
// ---------------------------------------------------------------------------
__global__ __launch_bounds__(256) void k_rowsum(const float* __restrict__ X,
                                                float* __restrict__ s) {
  const int row = blockIdx.x; // b*CC + c
  const float4* xr = reinterpret_cast<const float4*>(X + (size_t)row * NN);
  float acc = 0.f;
  for (int i = threadIdx.x; i < NN / 4; i += 256) {
    const float4 v = xr[i];
    acc += v.x + v.y + v.z + v.w;
  }
  __shared__ float red[256];
  red[threadIdx.x] = acc;
  __syncthreads();
  for (int off = 128; off > 0; off >>= 1) {
    if (threadIdx.x < off) red[threadIdx.x] += red[threadIdx.x + off];
    __syncthreads();
  }
  if (threadIdx.x == 0) s[row] = red[0];
}

// ---------------------------------------------------------------------------
// Gram split-K partials: Gp[b][ch][c][d] = sum_{n in chunk} X[c][n]*X[d][n]
// Grid: (2, 2, BB*NCH) = 512 blocks x 256 threads; 128x128 tile, BK=32.
// ---------------------------------------------------------------------------
__global__ __launch_bounds__(256) void k_gram(const float* __restrict__ X,
                                              float* __restrict__ Gp) {
  const int bz = blockIdx.z;
  const int b = bz >> 5;
  const int ch = bz & 31;
  const int c0 = blockIdx.y * 128;
  const int d0 = blockIdx.x * 128;
  const int nb = ch * CHK;
  const float* Xb = X + (size_t)b * CC * NN;

  __shared__ float As[32][128]; // As[k][c]
  __shared__ float Bs[32][128]; // Bs[k][d]

  const int tid = threadIdx.x;
  const int tm = tid >> 4;
  const int tn = tid & 15;
  const int l_row = tid >> 1;        // 0..127
  const int l_half = (tid & 1) * 16; // 0 or 16

  float acc[8][8];
#pragma unroll
  for (int i = 0; i < 8; ++i)
#pragma unroll
    for (int j = 0; j < 8; ++j) acc[i][j] = 0.f;

  for (int k0 = 0; k0 < CHK; k0 += 32) {
    float4 qa[4], ka[4];
#pragma unroll
    for (int j = 0; j < 4; ++j) {
      qa[j] = *reinterpret_cast<const float4*>(
          &Xb[(size_t)(c0 + l_row) * NN + nb + k0 + l_half + j * 4]);
      ka[j] = *reinterpret_cast<const float4*>(
          &Xb[(size_t)(d0 + l_row) * NN + nb + k0 + l_half + j * 4]);
    }
    __syncthreads();
#pragma unroll
    for (int j = 0; j < 4; ++j) {
      As[l_half + j * 4 + 0][l_row] = qa[j].x;
      As[l_half + j * 4 + 1][l_row] = qa[j].y;
      As[l_half + j * 4 + 2][l_row] = qa[j].z;
      As[l_half + j * 4 + 3][l_row] = qa[j].w;
      Bs[l_half + j * 4 + 0][l_row] = ka[j].x;
      Bs[l_half + j * 4 + 1][l_row] = ka[j].y;
      Bs[l_half + j * 4 + 2][l_row] = ka[j].z;
      Bs[l_half + j * 4 + 3][l_row] = ka[j].w;
    }
    __syncthreads();
#pragma unroll 8
    for (int kk = 0; kk < 32; ++kk) {
      const float4 a0 = *reinterpret_cast<const float4*>(&As[kk][tm * 4]);
      const float4 a1 = *reinterpret_cast<const float4*>(&As[kk][64 + tm * 4]);
      const float4 b0 = *reinterpret_cast<const float4*>(&Bs[kk][tn * 4]);
      const float4 b1 = *reinterpret_cast<const float4*>(&Bs[kk][64 + tn * 4]);
      const float a[8] = {a0.x, a0.y, a0.z, a0.w, a1.x, a1.y, a1.z, a1.w};
      const float bb[8] = {b0.x, b0.y, b0.z, b0.w, b1.x, b1.y, b1.z, b1.w};
#pragma unroll
      for (int i = 0; i < 8; ++i)
#pragma unroll
        for (int j = 0; j < 8; ++j) acc[i][j] += a[i] * bb[j];
    }
  }

  float* Sb = Gp + (size_t)(b * NCH + ch) * CC * CC;
#pragma unroll
  for (int i = 0; i < 8; ++i) {
    const int rr = c0 + ((i < 4) ? (tm * 4 + i) : (64 + tm * 4 + (i - 4)));
    float4 v0, v1;
    v0.x = acc[i][0]; v0.y = acc[i][1]; v0.z = acc[i][2]; v0.w = acc[i][3];
    v1.x = acc[i][4]; v1.y = acc[i][5]; v1.z = acc[i][6]; v1.w = acc[i][7];
    *reinterpret_cast<float4*>(&Sb[(size_t)rr * CC + d0 + tn * 4]) = v0;
    *reinterpret_cast<float4*>(&Sb[(size_t)rr * CC + d0 + 64 + tn * 4]) = v1;
  }
}

// ---------------------------------------------------------------------------
// G[b][c][d] = sum_ch Gp[b][ch][c][d].  Grid: BB*CC blocks x 256 threads.
// ---------------------------------------------------------------------------
__global__ __launch_bounds__(256) void k_red(const float* __restrict__ Gp,
                                             float* __restrict__ G) {
  const int b = blockIdx.x >> 8;
  const int c = blockIdx.x & 255;
  const int d = threadIdx.x;
  float acc = 0.f;
  for (int ch = 0; ch < NCH; ++ch)
    acc += Gp[((size_t)(b * NCH + ch) * CC + c) * CC + d];
  G[((size_t)b * CC + c) * CC + d] = acc;
}

// ---------------------------------------------------------------------------
// T[b] = Wq * G[b]   (256x256x256). Grid: (16, BB) blocks x 256 threads.
// Thread (cl = t>>4, dl = t&15) computes T[c0+cl][dl + 16*j], j=0..15.
// ---------------------------------------------------------------------------
__global__ __launch_bounds__(256) void k_T(const float* __restrict__ W,
                                           const float* __restrict__ G,
                                           float* __restrict__ T) {
  const int b = blockIdx.y;
  const int c0 = blockIdx.x * 16;
  const float* Gb = G + (size_t)b * CC * CC;

  __shared__ float As[16 * 33];  // [16][33] padded
  __shared__ float Bs[32 * 256]; // [32][256]

  const int t = threadIdx.x;
  const int cl = t >> 4;
  const int dl = t & 15;

  float acc[16];
#pragma unroll
  for (int j = 0; j < 16; ++j) acc[j] = 0.f;

  for (int e0 = 0; e0 < CC; e0 += 32) {
    __syncthreads();
    if (t < 128) { // A tile: 16 rows x 32 cols
      const float4 av = *reinterpret_cast<const float4*>(
          &W[(size_t)(c0 + (t >> 3)) * CC + e0 + (t & 7) * 4]);
      float* dst = &As[(t >> 3) * 33 + (t & 7) * 4];
      dst[0] = av.x; dst[1] = av.y; dst[2] = av.z; dst[3] = av.w;
    }
#pragma unroll
    for (int i = 0; i < 8; ++i) { // B tile: 32 rows x 256 cols
      const int idx = t + 256 * i;
      const int row = idx >> 6;
      const int c4 = (idx & 63) * 4;
      *reinterpret_cast<float4*>(&Bs[row * 256 + c4]) =
          *reinterpret_cast<const float4*>(&Gb[(size_t)(e0 + row) * CC + c4]);
    }
    __syncthreads();
#pragma unroll 8
    for (int e = 0; e < 32; ++e) {
      const float a = As[cl * 33 + e];
#pragma unroll
      for (int j = 0; j < 16; ++j) acc[j] += a * Bs[e * 256 + dl + 16 * j];
    }
  }
  float* Tb = T + (size_t)b * CC * CC;
#pragma unroll
  for (int j = 0; j < 16; ++j) Tb[(size_t)(c0 + cl) * CC + dl + 16 * j] = acc[j];
}

// ---------------------------------------------------------------------------
// Fused: S = T Wk^T + u bk^T + bq v^T, scale, softmax -> P; M = P Wv; r = P bv.
// u = Wq s + n bq, v = Wk s.  Grid: (16, BB) blocks x 256 threads.
// ---------------------------------------------------------------------------
__global__ __launch_bounds__(256) void k_soft(const float* __restrict__ T,
                                              const float* __restrict__ W,
                                              const float* __restrict__ bias,
                                              const float* __restrict__ s,
                                              float* __restrict__ M,
                                              float* __restrict__ r) {
  const int b = blockIdx.y;
  const int c0 = blockIdx.x * 16;
  const float* Tb = T + (size_t)b * CC * CC;
  const float* Wk = W + (size_t)CC * CC;
  const float* Wv = W + (size_t)2 * CC * CC;
  const float* bq = bias;
  const float* bk = bias + CC;
  const float* bv = bias + 2 * CC;
  const float* sb = s + b * CC;

  __shared__ float ss[256], vv[256], bks[256], bvs[256], us[16];
  __shared__ float buf[16 * 257 + 32 * 256]; // ph1: Wkt[32][257]+T_s[16][33]=8752
                                             // ph2: P_s[16][257]+Wv_s[32][256]=12304
  const int t = threadIdx.x;
  const int cl = t >> 4;
  const int dl = t & 15;

  ss[t] = sb[t];
  bks[t] = bk[t];
  bvs[t] = bv[t];
  __syncthreads();

  { // v[d] = dot(Wk[d], s)
    float a = 0.f;
    const float* wr = &Wk[(size_t)t * CC];
    for (int e = 0; e < CC; e += 4) {
      const float4 w4 = *reinterpret_cast<const float4*>(&wr[e]);
      a += w4.x * ss[e] + w4.y * ss[e + 1] + w4.z * ss[e + 2] + w4.w * ss[e + 3];
    }
    vv[t] = a;
  }
  if (t < 16) { // u for this block's 16 rows
    float a = 16384.f * bq[c0 + t];
    const float* wr = &W[(size_t)(c0 + t) * CC];
    for (int e = 0; e < CC; ++e) a += wr[e] * ss[e];
    us[t] = a;
  }

  float* Wkt = buf;             // [32][257] (f-major, padded)
  float* T_s = buf + 32 * 257;  // [16][33]
  float acc[16];
#pragma unroll
  for (int j = 0; j < 16; ++j) acc[j] = 0.f;

  for (int f0 = 0; f0 < CC; f0 += 32) {
    __syncthreads();
    if (t < 128) {
      const float4 tv = *reinterpret_cast<const float4*>(
          &Tb[(size_t)(c0 + (t >> 3)) * CC + f0 + (t & 7) * 4]);
      float* dst = &T_s[(t >> 3) * 33 + (t & 7) * 4];
      dst[0] = tv.x; dst[1] = tv.y; dst[2] = tv.z; dst[3] = tv.w;
    }
#pragma unroll
    for (int i = 0; i < 8; ++i) { // transpose-stage Wk[d][f0..f0+31] -> Wkt[f][d]
      const int idx = t + 256 * i;
      const int d = idx >> 3;
      const int k4 = (idx & 7) * 4;
      const float4 w4 =
          *reinterpret_cast<const float4*>(&Wk[(size_t)d * CC + f0 + k4]);
      Wkt[(k4 + 0) * 257 + d] = w4.x;
      Wkt[(k4 + 1) * 257 + d] = w4.y;
      Wkt[(k4 + 2) * 257 + d] = w4.z;
      Wkt[(k4 + 3) * 257 + d] = w4.w;
    }
    __syncthreads();
#pragma unroll 8
    for (int f = 0; f < 32; ++f) {
      const float a = T_s[cl * 33 + f];
#pragma unroll
      for (int j = 0; j < 16; ++j) acc[j] += a * Wkt[f * 257 + dl + 16 * j];
    }
  }

  // rank-1 terms + scale + softmax (row cl spans the 16 lanes of this shfl group)
  const float uu = us[cl];
  const float bqc = bq[c0 + cl];
#pragma unroll
  for (int j = 0; j < 16; ++j) {
    const int d = dl + 16 * j;
    acc[j] = (acc[j] + uu * bks[d] + bqc * vv[d]) * 0.0625f;
  }
  float mx = acc[0];
#pragma unroll
  for (int j = 1; j < 16; ++j) mx = fmaxf(mx, acc[j]);
#pragma unroll
  for (int msk = 8; msk; msk >>= 1) mx = fmaxf(mx, __shfl_xor(mx, msk, 16));
  float sum = 0.f;
#pragma unroll
  for (int j = 0; j < 16; ++j) {
    acc[j] = __expf(acc[j] - mx);
    sum += acc[j];
  }
#pragma unroll
  for (int msk = 8; msk; msk >>= 1) sum += __shfl_xor(sum, msk, 16);
  const float inv = 1.f / sum;

  __syncthreads(); // done reading Wkt/T_s; reuse buf
  float* P_s = buf;             // [16][257]
  float* Wv_s = buf + 16 * 257; // [32][256]
  float rloc = 0.f;
#pragma unroll
  for (int j = 0; j < 16; ++j) {
    const int d = dl + 16 * j;
    const float p = acc[j] * inv;
    P_s[cl * 257 + d] = p;
    rloc += p * bvs[d];
  }
#pragma unroll
  for (int msk = 8; msk; msk >>= 1) rloc += __shfl_xor(rloc, msk, 16);
  if (dl == 0) r[b * CC + c0 + cl] = rloc;

  float macc[16];
#pragma unroll
  for (int j = 0; j < 16; ++j) macc[j] = 0.f;
  for (int d0 = 0; d0 < CC; d0 += 32) {
    __syncthreads();
#pragma unroll
    for (int i = 0; i < 8; ++i) { // stage Wv[d0..d0+31][all]
      const int idx = t + 256 * i;
      const int row = idx >> 6;
      const int c4 = (idx & 63) * 4;
      *reinterpret_cast<float4*>(&Wv_s[row * 256 + c4]) =
          *reinterpret_cast<const float4*>(&Wv[(size_t)(d0 + row) * CC + c4]);
    }
    __syncthreads();
#pragma unroll 8
    for (int dd = 0; dd < 32; ++dd) {
      const float a = P_s[cl * 257 + d0 + dd];
#pragma unroll
      for (int j = 0; j < 16; ++j) macc[j] += a * Wv_s[dd * 256 + dl + 16 * j];
    }
  }
  float* Mb = M + (size_t)b * CC * CC;
#pragma unroll
  for (int j = 0; j < 16; ++j) Mb[(size_t)(c0 + cl) * CC + dl + 16 * j] = macc[j];
}

// ---------------------------------------------------------------------------
// out[b][c][n] = sum_d M[b][c][d] X[b][d][n] + r[b][c] + x[b][c][n]
// Grid: (NN/128, CC/128, BB) = (128, 2, 4) x 256 threads; 128x128 tile.
// Reads only M, r, X; writes every element of Out (so Out can host scratch
// for the earlier kernels).
// ---------------------------------------------------------------------------
__global__ __launch_bounds__(256) void k_out(const float* __restrict__ M,
                                             const float* __restrict__ r,
                                             const float* __restrict__ X,
                                             float* __restrict__ Out) {
  const int b = blockIdx.z;
  const int m0 = blockIdx.y * 128;
  const int n0 = blockIdx.x * 128;
  const float* A = M + (size_t)b * CC * CC;
  const float* Xb = X + (size_t)b * CC * NN;
  float* Ob = Out + (size_t)b * CC * NN;

  __shared__ float As[8][128];
  __shared__ float Bs[8][128];

  const int tid = threadIdx.x;
  const int tm = tid >> 4;
  const int tn = tid & 15;
  const int a_row = tid >> 1;
  const int a_col = (tid & 1) * 4;
  const int b_row = tid >> 5;
  const int b_col = (tid & 31) * 4;

  float acc[8][8];
#pragma unroll
  for (int i = 0; i < 8; ++i)
#pragma unroll
    for (int j = 0; j < 8; ++j) acc[i][j] = 0.f;

  for (int k0 = 0; k0 < CC; k0 += 8) {
    const float4 av = *reinterpret_cast<const float4*>(&A[(m0 + a_row) * CC + k0 + a_col]);
    const float4 bv = *reinterpret_cast<const float4*>(&Xb[(size_t)(k0 + b_row) * NN + n0 + b_col]);
    __syncthreads();
    As[a_col + 0][a_row] = av.x;
    As[a_col + 1][a_row] = av.y;
    As[a_col + 2][a_row] = av.z;
    As[a_col + 3][a_row] = av.w;
    *reinterpret_cast<float4*>(&Bs[b_row][b_col]) = bv;
    __syncthreads();
#pragma unroll
    for (int kk = 0; kk < 8; ++kk) {
      const float4 a0 = *reinterpret_cast<const float4*>(&As[kk][tm * 4]);
      const float4 a1 = *reinterpret_cast<const float4*>(&As[kk][64 + tm * 4]);
      const float4 b0 = *reinterpret_cast<const float4*>(&Bs[kk][tn * 4]);
      const float4 b1 = *reinterpret_cast<const float4*>(&Bs[kk][64 + tn * 4]);
      const float a[8] = {a0.x, a0.y, a0.z, a0.w, a1.x, a1.y, a1.z, a1.w};
      const float bb[8] = {b0.x, b0.y, b0.z, b0.w, b1.x, b1.y, b1.z, b1.w};
#pragma unroll
      for (int i = 0; i < 8; ++i)
#pragma unroll
        for (int j = 0; j < 8; ++j) acc[i][j] += a[i] * bb[j];
    }
  }

#pragma unroll
  for (int i = 0; i < 8; ++i) {
    const int m = m0 + ((i < 4) ? (tm * 4 + i) : (64 + tm * 4 + (i - 4)));
    const float rv = r[b * CC + m];
    const float4 x0 = *reinterpret_cast<const float4*>(&Xb[(size_t)m * NN + n0 + tn * 4]);
    const float4 x1 = *reinterpret_cast<const float4*>(&Xb[(size_t)m * NN + n0 + 64 + tn * 4]);
    float4 v0, v1;
    v0.x = acc[i][0] + rv + x0.x; v0.y = acc[i][1] + rv + x0.y;
    v0.z = acc[i][2] + rv + x0.z; v0.w = acc[i][3] + rv + x0.w;
    v1.x = acc[i][4] + rv + x1.x; v1.y = acc[i][5] + rv + x1.y;
    v1.z = acc[i][6] + rv + x1.z; v1.w = acc[i][7] + rv + x1.w;
    *reinterpret_cast<float4*>(&Ob[(size_t)m * NN + n0 + tn * 4]) = v0;
    *reinterpret_cast<float4*>(&Ob[(size_t)m * NN + n0 + 64 + tn * 4]) = v1;
  }
}

// ---------------------------------------------------------------------------
extern "C" void kernel_launch(void* const* d_in, const int* in_sizes, int n_in,
                              void* d_out, int out_size, void* d_ws, size_t ws_size,
                              hipStream_t stream) {
  const float* x = (const float*)d_in[0];     // [4][256][128][128]
  const float* w = (const float*)d_in[1];     // [768][256]
  const float* bias = (const float*)d_in[2];  // [768]
  float* out = (float*)d_out;

  // Big scratch lives in d_out (64 MB; fully overwritten by k_out at the end):
  float* Gp = out;                              // 4*32*256*256 = 32 MB
  float* G  = Gp + (size_t)BB * NCH * CC * CC;  // 4*256*256    =  1 MB
  float* Tm = G + (size_t)BB * CC * CC;         // 4*256*256    =  1 MB
  // Workspace holds only what k_out/k_soft still need (~1.02 MB):
  float* Mm = (float*)d_ws;                     // 4*256*256
  float* sV = Mm + (size_t)BB * CC * CC;        // 4*256
  float* rV = sV + (size_t)BB * CC;             // 4*256

  k_rowsum<<<BB * CC, 256, 0, stream>>>(x, sV);

  dim3 g2(2, 2, BB * NCH);
  k_gram<<<g2, 256, 0, stream>>>(x, Gp);

  k_red<<<BB * CC, 256, 0, stream>>>(Gp, G);

  dim3 g3(16, BB);
  k_T<<<g3, 256, 0, stream>>>(w, G, Tm);
  k_soft<<<g3, 256, 0, stream>>>(Tm, w, bias, sV, Mm, rV);

  dim3 g4(NN / 128, CC / 128, BB);
  k_out<<<g4, 256, 0, stream>>>(Mm, rV, x, out);
}

// Round 7
// 412.079 us; speedup vs baseline: 1.2900x; 1.2900x over previous
//
#include <hip/hip_runtime.h>

// Transposed (channel) attention via Gram decomposition, fp32, MI355X.
// b=4, c=256, n=16384.
//   G = X X^T (per batch), s = X 1
//   scores = Wq G Wk^T + u bk^T + bq v^T ; u = Wq s + n bq, v = Wk s
//   P = softmax(scores/16);  M = P Wv;  r = P bv
//   out = M X + r 1^T + x
//
// R5 fix: k_T + k_soft (64 blocks, 3% occupancy, 148 us) replaced by
// row-parallel k_fused (1024 blocks) + tiny k_wkt / k_uv precomputes.
// Scratch: Gp/G/WkT/u/v live in d_out (fully overwritten by k_out);
// ws holds only M/s/r (~1.02 MB).

#define BB 4
#define CC 256
#define NN 16384
#define NCH 32
#define CHK (NN / NCH) // 512

// ---------------------------------------------------------------------------
// s[b][c] = sum_n X[b][c][n].  Grid: BB*CC blocks x 256 threads.
// ---------------------------------------------------------------------------
__global__ __launch_bounds__(256) void k_rowsum(const float* __restrict__ X,
                                                float* __restrict__ s) {
  const int row = blockIdx.x; // b*CC + c
  const float4* xr = reinterpret_cast<const float4*>(X + (size_t)row * NN);
  float acc = 0.f;
  for (int i = threadIdx.x; i < NN / 4; i += 256) {
    const float4 v = xr[i];
    acc += v.x + v.y + v.z + v.w;
  }
  __shared__ float red[256];
  red[threadIdx.x] = acc;
  __syncthreads();
  for (int off = 128; off > 0; off >>= 1) {
    if (threadIdx.x < off) red[threadIdx.x] += red[threadIdx.x + off];
    __syncthreads();
  }
  if (threadIdx.x == 0) s[row] = red[0];
}

// ---------------------------------------------------------------------------
// WkT[f][d] = Wk[d][f].  Grid: (8,8) x 256 threads, 32x32 LDS tiles.
// ---------------------------------------------------------------------------
__global__ __launch_bounds__(256) void k_wkt(const float* __restrict__ W,
                                             float* __restrict__ WkT) {
  const float* Wk = W + (size_t)CC * CC;
  __shared__ float tile[32][33];
  const int bx = blockIdx.x, by = blockIdx.y;
  const int tx = threadIdx.x & 31, ty = threadIdx.x >> 5; // 32 x 8
#pragma unroll
  for (int r = 0; r < 32; r += 8)
    tile[ty + r][tx] = Wk[(size_t)(by * 32 + ty + r) * CC + bx * 32 + tx];
  __syncthreads();
#pragma unroll
  for (int r = 0; r < 32; r += 8)
    WkT[(size_t)(bx * 32 + ty + r) * CC + by * 32 + tx] = tile[tx][ty + r];
}

// ---------------------------------------------------------------------------
// u[b][c] = dot(Wq[c], s_b) + n*bq[c];  v[b][d] = dot(Wk[d], s_b).
// Grid: BB blocks x 256 threads.
// ---------------------------------------------------------------------------
__global__ __launch_bounds__(256) void k_uv(const float* __restrict__ W,
                                            const float* __restrict__ bias,
                                            const float* __restrict__ s,
                                            float* __restrict__ u,
                                            float* __restrict__ v) {
  const int b = blockIdx.x;
  const int t = threadIdx.x;
  __shared__ float ssm[256];
  ssm[t] = s[b * CC + t];
  __syncthreads();
  const float* wq = W + (size_t)t * CC;
  const float* wk = W + (size_t)CC * CC + (size_t)t * CC;
  float au = 0.f, av = 0.f;
  for (int e = 0; e < CC; e += 4) {
    const float4 a = *reinterpret_cast<const float4*>(wq + e);
    const float4 c = *reinterpret_cast<const float4*>(wk + e);
    au += a.x * ssm[e] + a.y * ssm[e + 1] + a.z * ssm[e + 2] + a.w * ssm[e + 3];
    av += c.x * ssm[e] + c.y * ssm[e + 1] + c.z * ssm[e + 2] + c.w * ssm[e + 3];
  }
  u[b * CC + t] = au + 16384.f * bias[t];
  v[b * CC + t] = av;
}

// ---------------------------------------------------------------------------
// Gram split-K partials: Gp[b][ch][c][d] = sum_{n in chunk} X[c][n]*X[d][n]
// Grid: (2, 2, BB*NCH) = 512 blocks x 256 threads; 128x128 tile, BK=32.
// ---------------------------------------------------------------------------
__global__ __launch_bounds__(256) void k_gram(const float* __restrict__ X,
                                              float* __restrict__ Gp) {
  const int bz = blockIdx.z;
  const int b = bz >> 5;
  const int ch = bz & 31;
  const int c0 = blockIdx.y * 128;
  const int d0 = blockIdx.x * 128;
  const int nb = ch * CHK;
  const float* Xb = X + (size_t)b * CC * NN;

  __shared__ float As[32][128]; // As[k][c]
  __shared__ float Bs[32][128]; // Bs[k][d]

  const int tid = threadIdx.x;
  const int tm = tid >> 4;
  const int tn = tid & 15;
  const int l_row = tid >> 1;        // 0..127
  const int l_half = (tid & 1) * 16; // 0 or 16

  float acc[8][8];
#pragma unroll
  for (int i = 0; i < 8; ++i)
#pragma unroll
    for (int j = 0; j < 8; ++j) acc[i][j] = 0.f;

  for (int k0 = 0; k0 < CHK; k0 += 32) {
    float4 qa[4], ka[4];
#pragma unroll
    for (int j = 0; j < 4; ++j) {
      qa[j] = *reinterpret_cast<const float4*>(
          &Xb[(size_t)(c0 + l_row) * NN + nb + k0 + l_half + j * 4]);
      ka[j] = *reinterpret_cast<const float4*>(
          &Xb[(size_t)(d0 + l_row) * NN + nb + k0 + l_half + j * 4]);
    }
    __syncthreads();
#pragma unroll
    for (int j = 0; j < 4; ++j) {
      As[l_half + j * 4 + 0][l_row] = qa[j].x;
      As[l_half + j * 4 + 1][l_row] = qa[j].y;
      As[l_half + j * 4 + 2][l_row] = qa[j].z;
      As[l_half + j * 4 + 3][l_row] = qa[j].w;
      Bs[l_half + j * 4 + 0][l_row] = ka[j].x;
      Bs[l_half + j * 4 + 1][l_row] = ka[j].y;
      Bs[l_half + j * 4 + 2][l_row] = ka[j].z;
      Bs[l_half + j * 4 + 3][l_row] = ka[j].w;
    }
    __syncthreads();
#pragma unroll 8
    for (int kk = 0; kk < 32; ++kk) {
      const float4 a0 = *reinterpret_cast<const float4*>(&As[kk][tm * 4]);
      const float4 a1 = *reinterpret_cast<const float4*>(&As[kk][64 + tm * 4]);
      const float4 b0 = *reinterpret_cast<const float4*>(&Bs[kk][tn * 4]);
      const float4 b1 = *reinterpret_cast<const float4*>(&Bs[kk][64 + tn * 4]);
      const float a[8] = {a0.x, a0.y, a0.z, a0.w, a1.x, a1.y, a1.z, a1.w};
      const float bb[8] = {b0.x, b0.y, b0.z, b0.w, b1.x, b1.y, b1.z, b1.w};
#pragma unroll
      for (int i = 0; i < 8; ++i)
#pragma unroll
        for (int j = 0; j < 8; ++j) acc[i][j] += a[i] * bb[j];
    }
  }

  float* Sb = Gp + (size_t)(b * NCH + ch) * CC * CC;
#pragma unroll
  for (int i = 0; i < 8; ++i) {
    const int rr = c0 + ((i < 4) ? (tm * 4 + i) : (64 + tm * 4 + (i - 4)));
    float4 v0, v1;
    v0.x = acc[i][0]; v0.y = acc[i][1]; v0.z = acc[i][2]; v0.w = acc[i][3];
    v1.x = acc[i][4]; v1.y = acc[i][5]; v1.z = acc[i][6]; v1.w = acc[i][7];
    *reinterpret_cast<float4*>(&Sb[(size_t)rr * CC + d0 + tn * 4]) = v0;
    *reinterpret_cast<float4*>(&Sb[(size_t)rr * CC + d0 + 64 + tn * 4]) = v1;
  }
}

// ---------------------------------------------------------------------------
// G[b][c][d] = sum_ch Gp[b][ch][c][d].  Grid: BB*CC blocks x 256 threads.
// ---------------------------------------------------------------------------
__global__ __launch_bounds__(256) void k_red(const float* __restrict__ Gp,
                                             float* __restrict__ G) {
  const int b = blockIdx.x >> 8;
  const int c = blockIdx.x & 255;
  const int d = threadIdx.x;
  float acc = 0.f;
  for (int ch = 0; ch < NCH; ++ch)
    acc += Gp[((size_t)(b * NCH + ch) * CC + c) * CC + d];
  G[((size_t)b * CC + c) * CC + d] = acc;
}

// ---------------------------------------------------------------------------
// Row-parallel fused score/softmax/M kernel. Grid: (CC, BB) = 1024 blocks
// x 256 threads. Block (c, b):
//   T_row = Wq[c] * G_b            (coalesced G-row reads)
//   S_row = T_row * WkT + u[c]*bk + bq[c]*v ; scale 1/16
//   P = softmax(S_row)  (block-wide reduce)
//   M[c] = P * Wv ; r[c] = P . bv
// ---------------------------------------------------------------------------
__global__ __launch_bounds__(256) void k_fused(const float* __restrict__ G,
                                               const float* __restrict__ WkT,
                                               const float* __restrict__ W,
                                               const float* __restrict__ bias,
                                               const float* __restrict__ u,
                                               const float* __restrict__ v,
                                               float* __restrict__ M,
                                               float* __restrict__ r) {
  const int c = blockIdx.x;
  const int b = blockIdx.y;
  const int t = threadIdx.x;
  const int lane = t & 63, wid = t >> 6;
  const float* Gb = G + (size_t)b * CC * CC;
  const float* Wv = W + (size_t)2 * CC * CC;
  const float* bk = bias + CC;
  const float* bv = bias + 2 * CC;

  __shared__ float sa[256];   // Wq row -> P row
  __shared__ float sb2[256];  // T row
  __shared__ float redbuf[4];

  sa[t] = W[(size_t)c * CC + t]; // Wq[c][:]
  __syncthreads();

  // T_row[t] = sum_f Wq[c][f] * G[f][t]
  float acc = 0.f;
#pragma unroll 4
  for (int f = 0; f < CC; ++f) acc += sa[f] * Gb[(size_t)f * CC + t];
  sb2[t] = acc;
  __syncthreads();

  // S_row[t] = sum_f T_row[f] * WkT[f][t] + u[c]*bk[t] + bq[c]*v[t]
  float sacc = 0.f;
#pragma unroll 4
  for (int f = 0; f < CC; ++f) sacc += sb2[f] * WkT[(size_t)f * CC + t];
  const float uu = u[b * CC + c];
  const float bqc = bias[c];
  sacc = (sacc + uu * bk[t] + bqc * v[b * CC + t]) * 0.0625f;

  // block softmax over 256 values (one per thread)
  float mx = sacc;
#pragma unroll
  for (int m = 32; m; m >>= 1) mx = fmaxf(mx, __shfl_xor(mx, m));
  if (lane == 0) redbuf[wid] = mx;
  __syncthreads();
  mx = fmaxf(fmaxf(redbuf[0], redbuf[1]), fmaxf(redbuf[2], redbuf[3]));
  const float ev = __expf(sacc - mx);
  float sum = ev;
#pragma unroll
  for (int m = 32; m; m >>= 1) sum += __shfl_xor(sum, m);
  __syncthreads(); // all reads of redbuf(max) done
  if (lane == 0) redbuf[wid] = sum;
  __syncthreads();
  sum = redbuf[0] + redbuf[1] + redbuf[2] + redbuf[3];
  const float p = ev / sum;

  sa[t] = p; // reuse sa for P row (last read of sa was step 1, long done)
  // r[c] = sum_d P[d]*bv[d]
  float rloc = p * bv[t];
#pragma unroll
  for (int m = 32; m; m >>= 1) rloc += __shfl_xor(rloc, m);
  __syncthreads(); // P visible; redbuf reads done
  if (lane == 0) redbuf[wid] = rloc;
  __syncthreads();
  if (t == 0) r[b * CC + c] = redbuf[0] + redbuf[1] + redbuf[2] + redbuf[3];

  // M_row[t] = sum_d P[d] * Wv[d][t]
  float macc = 0.f;
#pragma unroll 4
  for (int d = 0; d < CC; ++d) macc += sa[d] * Wv[(size_t)d * CC + t];
  M[((size_t)b * CC + c) * CC + t] = macc;
}

// ---------------------------------------------------------------------------
// out[b][c][n] = sum_d M[b][c][d] X[b][d][n] + r[b][c] + x[b][c][n]
// Grid: (NN/128, CC/128, BB) = (128, 2, 4) x 256 threads; 128x128 tile.
// Reads only M, r, X; writes every element of Out.
// ---------------------------------------------------------------------------
__global__ __launch_bounds__(256) void k_out(const float* __restrict__ M,
                                             const float* __restrict__ r,
                                             const float* __restrict__ X,
                                             float* __restrict__ Out) {
  const int b = blockIdx.z;
  const int m0 = blockIdx.y * 128;
  const int n0 = blockIdx.x * 128;
  const float* A = M + (size_t)b * CC * CC;
  const float* Xb = X + (size_t)b * CC * NN;
  float* Ob = Out + (size_t)b * CC * NN;

  __shared__ float As[8][128];
  __shared__ float Bs[8][128];

  const int tid = threadIdx.x;
  const int tm = tid >> 4;
  const int tn = tid & 15;
  const int a_row = tid >> 1;
  const int a_col = (tid & 1) * 4;
  const int b_row = tid >> 5;
  const int b_col = (tid & 31) * 4;

  float acc[8][8];
#pragma unroll
  for (int i = 0; i < 8; ++i)
#pragma unroll
    for (int j = 0; j < 8; ++j) acc[i][j] = 0.f;

  for (int k0 = 0; k0 < CC; k0 += 8) {
    const float4 av = *reinterpret_cast<const float4*>(&A[(m0 + a_row) * CC + k0 + a_col]);
    const float4 bv = *reinterpret_cast<const float4*>(&Xb[(size_t)(k0 + b_row) * NN + n0 + b_col]);
    __syncthreads();
    As[a_col + 0][a_row] = av.x;
    As[a_col + 1][a_row] = av.y;
    As[a_col + 2][a_row] = av.z;
    As[a_col + 3][a_row] = av.w;
    *reinterpret_cast<float4*>(&Bs[b_row][b_col]) = bv;
    __syncthreads();
#pragma unroll
    for (int kk = 0; kk < 8; ++kk) {
      const float4 a0 = *reinterpret_cast<const float4*>(&As[kk][tm * 4]);
      const float4 a1 = *reinterpret_cast<const float4*>(&As[kk][64 + tm * 4]);
      const float4 b0 = *reinterpret_cast<const float4*>(&Bs[kk][tn * 4]);
      const float4 b1 = *reinterpret_cast<const float4*>(&Bs[kk][64 + tn * 4]);
      const float a[8] = {a0.x, a0.y, a0.z, a0.w, a1.x, a1.y, a1.z, a1.w};
      const float bb[8] = {b0.x, b0.y, b0.z, b0.w, b1.x, b1.y, b1.z, b1.w};
#pragma unroll
      for (int i = 0; i < 8; ++i)
#pragma unroll
        for (int j = 0; j < 8; ++j) acc[i][j] += a[i] * bb[j];
    }
  }

#pragma unroll
  for (int i = 0; i < 8; ++i) {
    const int m = m0 + ((i < 4) ? (tm * 4 + i) : (64 + tm * 4 + (i - 4)));
    const float rv = r[b * CC + m];
    const float4 x0 = *reinterpret_cast<const float4*>(&Xb[(size_t)m * NN + n0 + tn * 4]);
    const float4 x1 = *reinterpret_cast<const float4*>(&Xb[(size_t)m * NN + n0 + 64 + tn * 4]);
    float4 v0, v1;
    v0.x = acc[i][0] + rv + x0.x; v0.y = acc[i][1] + rv + x0.y;
    v0.z = acc[i][2] + rv + x0.z; v0.w = acc[i][3] + rv + x0.w;
    v1.x = acc[i][4] + rv + x1.x; v1.y = acc[i][5] + rv + x1.y;
    v1.z = acc[i][6] + rv + x1.z; v1.w = acc[i][7] + rv + x1.w;
    *reinterpret_cast<float4*>(&Ob[(size_t)m * NN + n0 + tn * 4]) = v0;
    *reinterpret_cast<float4*>(&Ob[(size_t)m * NN + n0 + 64 + tn * 4]) = v1;
  }
}

// ---------------------------------------------------------------------------
extern "C" void kernel_launch(void* const* d_in, const int* in_sizes, int n_in,
                              void* d_out, int out_size, void* d_ws, size_t ws_size,
                              hipStream_t stream) {
  const float* x = (const float*)d_in[0];     // [4][256][128][128]
  const float* w = (const float*)d_in[1];     // [768][256]
  const float* bias = (const float*)d_in[2];  // [768]
  float* out = (float*)d_out;

  // Scratch in d_out (64 MB; fully overwritten by k_out at the end):
  float* Gp  = out;                              // 4*32*256*256 = 32 MB
  float* G   = Gp + (size_t)BB * NCH * CC * CC;  // 4*256*256    =  1 MB
  float* WkT = G + (size_t)BB * CC * CC;         // 256*256      = .25 MB
  float* uV  = WkT + (size_t)CC * CC;            // 4*256
  float* vV  = uV + (size_t)BB * CC;             // 4*256
  // Workspace (~1.02 MB): only what k_out / k_fused outputs need.
  float* Mm = (float*)d_ws;                      // 4*256*256
  float* sV = Mm + (size_t)BB * CC * CC;         // 4*256
  float* rV = sV + (size_t)BB * CC;              // 4*256

  k_rowsum<<<BB * CC, 256, 0, stream>>>(x, sV);

  dim3 gt(8, 8);
  k_wkt<<<gt, 256, 0, stream>>>(w, WkT);

  dim3 g2(2, 2, BB * NCH);
  k_gram<<<g2, 256, 0, stream>>>(x, Gp);

  k_red<<<BB * CC, 256, 0, stream>>>(Gp, G);

  k_uv<<<BB, 256, 0, stream>>>(w, bias, sV, uV, vV);

  dim3 gf(CC, BB);
  k_fused<<<gf, 256, 0, stream>>>(G, WkT, w, bias, uV, vV, Mm, rV);

  dim3 g4(NN / 128, CC / 128, BB);
  k_out<<<g4, 256, 0, stream>>>(Mm, rV, x, out);
}